// Round 10
// baseline (170.616 us; speedup 1.0000x reference)
//
#include <hip/hip_runtime.h>
#include <hip/hip_bf16.h>

#define HH 128
#define WW 128
#define CC 64
#define TT 5
#define HW (HH*WW)
#define NI 10

typedef __attribute__((ext_vector_type(8))) short short8;
typedef __attribute__((ext_vector_type(4))) float f32x4;

__device__ __forceinline__ float bf2f(unsigned int bits16) {
  union { unsigned int u; float f; } v; v.u = bits16 << 16; return v.f;
}
__device__ __forceinline__ unsigned short f2bf(float f) {
  __hip_bfloat16 h = __float2bfloat16(f);
  return *reinterpret_cast<unsigned short*>(&h);
}

// ---- merged pack: blocks [0, NI*HH) transpose x; blocks [NI*HH, +144) pack weights.
__global__ __launch_bounds__(256) void pack_k(const float* __restrict__ x,
    const float* __restrict__ w1, const float* __restrict__ w2,
    unsigned short* __restrict__ xb, unsigned short* __restrict__ wb1,
    unsigned short* __restrict__ wb2) {
  __shared__ unsigned short tb[128*65];
  const int tid = threadIdx.x;
  const int bx = blockIdx.x;
  if (bx >= NI*HH) {            // ---- weight part
    int idx = (bx - NI*HH)*256 + tid;
    if (idx < 64*576) {
      int oc = idx / 576, rem = idx - oc*576, kk = rem >> 6, ic = rem & 63;
      wb1[idx] = f2bf(w1[(oc*64 + ic)*9 + kk]);
    }
    if (idx < 16*576) {
      int oc = idx / 576, rem = idx - oc*576, kk = rem >> 6, ic = rem & 63;
      wb2[idx] = (oc < 9) ? f2bf(w2[(oc*64 + ic)*9 + kk]) : (unsigned short)0;
    }
    return;
  }
  const int n = bx >> 7, h = bx & 127;
  const int bi = n / 5, ti = n - bi*5;
  const float* xp = x + ((size_t)bi*CC*TT + ti)*HW + (size_t)h*WW;
  for (int e = tid; e < 64*128; e += 256) {
    int ci = e >> 7, w = e & 127;
    tb[w*65 + ci] = f2bf(xp[(size_t)ci*TT*HW + w]);
  }
  __syncthreads();
  unsigned short* dst = xb + ((size_t)n*HW + (size_t)h*WW)*64;
  for (int e = tid; e < 2048; e += 256) {
    int w = e >> 4, c = e & 15;
    *(uint2*)(dst + w*64 + c*4) = *(const uint2*)(&tb[w*65 + c*4]);
  }
}

// ---- conv1 v6 (frozen): both operands in LDS + B-frag reuse.
__global__ __launch_bounds__(256, 2) void conv1_mfma(
    const unsigned short* __restrict__ xb, const unsigned short* __restrict__ wb1,
    const float* __restrict__ b1, unsigned short* __restrict__ yb) {
  __shared__ unsigned short xt[324*64];    // 18x18 halo x 64 ic = 41472 B
  __shared__ unsigned short wt[36*512];    // 36 frags x 64 lanes x 8 shorts = 36864 B
  const int tid = threadIdx.x;
  const int wave = tid >> 6, lane = tid & 63, q = lane >> 4, r = lane & 15;
  const int n = blockIdx.z >> 1, ocg = (blockIdx.z & 1) << 5;
  const int h0 = blockIdx.y << 4, w0 = blockIdx.x << 4;
  const unsigned short* xn = xb + (size_t)n*HW*64;

  {
    const unsigned short* wsrc = wb1 + (size_t)ocg*576;
    for (int e = tid; e < 2304; e += 256) {
      int frag = e >> 6, ln = e & 63;
      int kk = frag >> 2, rem = frag & 3, half = rem >> 1, g = rem & 1;
      *(uint4*)(&wt[e << 3]) = *(const uint4*)(
          wsrc + (size_t)(g*16 + (ln & 15))*576 + kk*64 + half*32 + ((ln >> 4) << 3));
    }
  }
  for (int e = tid; e < 2592; e += 256) {           // 324 sp x 8 chunks, 16B
    int sp = e >> 3, c = e & 7;
    int sr = sp / 18, sc = sp - sr*18;
    int gh = h0 + sr - 1, gw = w0 + sc - 1;
    uint4 v = make_uint4(0u,0u,0u,0u);
    if (gh >= 0 && gh < HH && gw >= 0 && gw < WW)
      v = *(const uint4*)(xn + ((size_t)(gh*WW + gw))*64 + (c << 3));
    *(uint4*)(&xt[sp*64 + ((c ^ (sp & 7)) << 3)]) = v;
  }
  __syncthreads();

  f32x4 zero4 = {0.f, 0.f, 0.f, 0.f};
  f32x4 acc[4][2];
  #pragma unroll
  for (int i = 0; i < 4; ++i)
    #pragma unroll
    for (int g = 0; g < 2; ++g) acc[i][g] = zero4;

  #pragma unroll
  for (int half = 0; half < 2; ++half) {
    short8 bf[6][3];
    #pragma unroll
    for (int rr = 0; rr < 6; ++rr)
      #pragma unroll
      for (int dx = 0; dx < 3; ++dx) {
        int sp = (wave*4 + rr)*18 + (r + dx);
        bf[rr][dx] = *(const short8*)(&xt[sp*64 + ((((half << 2) | q) ^ (sp & 7)) << 3)]);
      }
    #pragma unroll
    for (int kk = 0; kk < 9; ++kk) {
      const int dy = kk / 3, dx = kk - dy*3;
      short8 a0 = *(const short8*)(&wt[((kk*4 + half*2 + 0) << 9) + (lane << 3)]);
      short8 a1 = *(const short8*)(&wt[((kk*4 + half*2 + 1) << 9) + (lane << 3)]);
      #pragma unroll
      for (int i = 0; i < 4; ++i) {
        acc[i][0] = __builtin_amdgcn_mfma_f32_16x16x32_bf16(a0, bf[i+dy][dx], acc[i][0], 0, 0, 0);
        acc[i][1] = __builtin_amdgcn_mfma_f32_16x16x32_bf16(a1, bf[i+dy][dx], acc[i][1], 0, 0, 0);
      }
    }
  }

  #pragma unroll
  for (int i = 0; i < 4; ++i) {
    int py = wave*4 + i;
    unsigned short* yp = yb + ((size_t)n*HW + (h0+py)*WW + (w0+r))*64;
    #pragma unroll
    for (int g = 0; g < 2; ++g) {
      int oc0 = ocg + g*16 + (q << 2);
      f32x4 bias = *(const f32x4*)(b1 + oc0);
      float v0 = acc[i][g][0] + bias[0]; v0 = (v0 >= 0.f) ? v0 : 0.2f*v0;
      float v1 = acc[i][g][1] + bias[1]; v1 = (v1 >= 0.f) ? v1 : 0.2f*v1;
      float v2 = acc[i][g][2] + bias[2]; v2 = (v2 >= 0.f) ? v2 : 0.2f*v2;
      float v3 = acc[i][g][3] + bias[3]; v3 = (v3 >= 0.f) ? v3 : 0.2f*v3;
      uint2 pk;
      pk.x = (unsigned int)f2bf(v0) | ((unsigned int)f2bf(v1) << 16);
      pk.y = (unsigned int)f2bf(v2) | ((unsigned int)f2bf(v3) << 16);
      *(uint2*)(yp + oc0) = pk;
    }
  }
}

// ---- conv2 v6 (frozen)
__global__ __launch_bounds__(256) void conv2_mfma(
    const unsigned short* __restrict__ yb, const unsigned short* __restrict__ wb2,
    const float* __restrict__ b2, float* __restrict__ ker0) {
  __shared__ unsigned short yt[180*64];
  __shared__ unsigned short wt[18*512];
  const int tid = threadIdx.x;
  const int wave = tid >> 6, lane = tid & 63, q = lane >> 4, r = lane & 15;
  const int n = blockIdx.z;
  const int h0 = blockIdx.y << 3, w0 = blockIdx.x << 4;
  const unsigned short* yn = yb + (size_t)n*HW*64;

  for (int e = tid; e < 1152; e += 256) {
    int frag = e >> 6, ln = e & 63;
    int kk = frag >> 1, half = frag & 1;
    *(uint4*)(&wt[e << 3]) = *(const uint4*)(
        wb2 + (size_t)(ln & 15)*576 + kk*64 + half*32 + ((ln >> 4) << 3));
  }
  for (int e = tid; e < 1440; e += 256) {
    int sp = e >> 3, c = e & 7;
    int sr = sp / 18, sc = sp - sr*18;
    int gh = h0 + sr - 1, gw = w0 + sc - 1;
    uint4 v = make_uint4(0u,0u,0u,0u);
    if (gh >= 0 && gh < HH && gw >= 0 && gw < WW)
      v = *(const uint4*)(yn + ((size_t)(gh*WW + gw))*64 + (c << 3));
    *(uint4*)(&yt[sp*64 + ((c ^ (sp & 7)) << 3)]) = v;
  }
  __syncthreads();

  f32x4 zero4 = {0.f, 0.f, 0.f, 0.f};
  f32x4 acc[2];
  #pragma unroll
  for (int i = 0; i < 2; ++i) acc[i] = zero4;

  #pragma unroll
  for (int half = 0; half < 2; ++half) {
    short8 bf[4][3];
    #pragma unroll
    for (int rr = 0; rr < 4; ++rr)
      #pragma unroll
      for (int dx = 0; dx < 3; ++dx) {
        int sp = (wave*2 + rr)*18 + (r + dx);
        bf[rr][dx] = *(const short8*)(&yt[sp*64 + ((((half << 2) | q) ^ (sp & 7)) << 3)]);
      }
    #pragma unroll
    for (int kk = 0; kk < 9; ++kk) {
      const int dy = kk / 3, dx = kk - dy*3;
      short8 a = *(const short8*)(&wt[((kk*2 + half) << 9) + (lane << 3)]);
      #pragma unroll
      for (int i = 0; i < 2; ++i)
        acc[i] = __builtin_amdgcn_mfma_f32_16x16x32_bf16(a, bf[i+dy][dx], acc[i], 0, 0, 0);
    }
  }

  #pragma unroll
  for (int i = 0; i < 2; ++i) {
    int py = wave*2 + i;
    #pragma unroll
    for (int t2 = 0; t2 < 4; ++t2) {
      int oc = (q << 2) + t2;
      if (oc < 9)
        ker0[((size_t)n*9 + oc)*HW + (h0+py)*WW + w0 + r] = acc[i][t2] + b2[oc];
    }
  }
}

// ---- dynamic filtering v5: 8x8 px tile, ALL 64 ci per block (16 rounds x 4 ci).
// Block's xb working set = 500 lines x 128B = 64 KB -> stays in its XCD L2
// across rounds: each line fetched from L3 once, 15x L2 hits (kills the 16x
// L3 over-fetch of the per-ci-block scheme). grid (16,16,2) = 512 blocks.
// cq = tid>>6 is wave-uniform; xs stride 5 (gcd(5,32)=1) keeps banks spread.
__global__ __launch_bounds__(256) void dynf_k(
    const unsigned short* __restrict__ xb, const float* __restrict__ ker0,
    float* __restrict__ out) {
  __shared__ float xs[TT*100*5];           // [t5*100+sp][4ci + pad] = 10000 B
  const int tid = threadIdx.x;
  const int px = tid & 63, cq = tid >> 6;  // wave-uniform ci sub-index
  const int pw = px & 7, ph = px >> 3;
  const int bi = blockIdx.z;
  const int h0 = blockIdx.y << 3, w0 = blockIdx.x << 3;
  const int pix = (h0+ph)*WW + w0 + pw;

  // per-thread normalized kernel (redundant across the 4 cq-waves)
  float kv[45]; float s = 0.f;
  #pragma unroll
  for (int t5 = 0; t5 < TT; ++t5)
    #pragma unroll
    for (int kk = 0; kk < 9; ++kk) {
      float v = ker0[((size_t)(bi*TT + t5)*9 + kk)*HW + pix];
      kv[t5*9 + kk] = v; s += v;
    }
  const float m = (s - 1.f) * (1.f/45.f);
  #pragma unroll
  for (int qq = 0; qq < 45; ++qq) kv[qq] -= m;

  for (int rnd = 0; rnd < 16; ++rnd) {
    __syncthreads();                       // xs consumed by previous round
    for (int e = tid; e < TT*100; e += 256) {
      int t5 = e / 100, sp = e - t5*100;
      int rr2 = sp / 10, cc = sp - rr2*10;
      int gh = min(max(h0 + rr2 - 1, 0), HH-1);
      int gw = min(max(w0 + cc - 1, 0), WW-1);
      uint2 raw = *(const uint2*)(xb + ((size_t)(bi*TT + t5)*HW + gh*WW + gw)*64 + (rnd << 2));
      float* d = &xs[e*5];
      d[0] = bf2f(raw.x & 0xffffu);
      d[1] = bf2f(raw.x >> 16);
      d[2] = bf2f(raw.y & 0xffffu);
      d[3] = bf2f(raw.y >> 16);
    }
    __syncthreads();
    float a = 0.f;
    #pragma unroll
    for (int t5 = 0; t5 < TT; ++t5)
      #pragma unroll
      for (int dy = 0; dy < 3; ++dy)
        #pragma unroll
        for (int dx = 0; dx < 3; ++dx)
          a = fmaf(xs[(t5*100 + (ph+dy)*10 + pw+dx)*5 + cq],
                   kv[t5*9 + dy*3 + dx], a);
    out[((size_t)(bi*CC + (rnd << 2) + cq))*HW + pix] = a;
  }
}

extern "C" void kernel_launch(void* const* d_in, const int* in_sizes, int n_in,
                              void* d_out, int out_size, void* d_ws, size_t ws_size,
                              hipStream_t stream) {
  const float* x  = (const float*)d_in[0];
  const float* w1 = (const float*)d_in[1];
  const float* b1 = (const float*)d_in[2];
  const float* w2 = (const float*)d_in[3];
  const float* b2 = (const float*)d_in[4];
  float* out = (float*)d_out;

  unsigned short* xb  = (unsigned short*)d_ws;
  unsigned short* yb  = xb + (size_t)NI*HW*64;
  float*          ker0 = (float*)(yb + (size_t)NI*HW*64);
  unsigned short* wb1 = (unsigned short*)(ker0 + (size_t)NI*9*HW);
  unsigned short* wb2 = wb1 + 64*576;

  pack_k    <<<NI*HH + 144, 256, 0, stream>>>(x, w1, w2, xb, wb1, wb2);
  conv1_mfma<<<dim3(8,8,2*NI), 256, 0, stream>>>(xb, wb1, b1, yb);
  conv2_mfma<<<dim3(8,16,NI), 256, 0, stream>>>(yb, wb2, b2, ker0);
  dynf_k    <<<dim3(16,16,2), 256, 0, stream>>>(xb, ker0, out);
}

// Round 11
// 148.523 us; speedup vs baseline: 1.1488x; 1.1488x over previous
//
#include <hip/hip_runtime.h>
#include <hip/hip_bf16.h>

#define HH 128
#define WW 128
#define CC 64
#define TT 5
#define HW (HH*WW)
#define NI 10

typedef __attribute__((ext_vector_type(8))) short short8;
typedef __attribute__((ext_vector_type(4))) float f32x4;

__device__ __forceinline__ float bf2f(unsigned int bits16) {
  union { unsigned int u; float f; } v; v.u = bits16 << 16; return v.f;
}
__device__ __forceinline__ unsigned short f2bf(float f) {
  __hip_bfloat16 h = __float2bfloat16(f);
  return *reinterpret_cast<unsigned short*>(&h);
}

// ---- merged pack (R8 config, stride 68): x transpose + weight pack.
__global__ __launch_bounds__(256) void pack_k(const float* __restrict__ x,
    const float* __restrict__ w1, const float* __restrict__ w2,
    unsigned short* __restrict__ xb, unsigned short* __restrict__ wb1,
    unsigned short* __restrict__ wb2) {
  __shared__ unsigned short tb[128*68];
  const int tid = threadIdx.x;
  const int bx = blockIdx.x;
  if (bx >= NI*HH) {            // ---- weight part
    int idx = (bx - NI*HH)*256 + tid;
    if (idx < 64*576) {
      int oc = idx / 576, rem = idx - oc*576, kk = rem >> 6, ic = rem & 63;
      wb1[idx] = f2bf(w1[(oc*64 + ic)*9 + kk]);
    }
    if (idx < 16*576) {
      int oc = idx / 576, rem = idx - oc*576, kk = rem >> 6, ic = rem & 63;
      wb2[idx] = (oc < 9) ? f2bf(w2[(oc*64 + ic)*9 + kk]) : (unsigned short)0;
    }
    return;
  }
  const int n = bx >> 7, h = bx & 127;
  const int bi = n / 5, ti = n - bi*5;
  const float* xp = x + ((size_t)bi*CC*TT + ti)*HW + (size_t)h*WW;
  for (int e = tid; e < 64*128; e += 256) {
    int ci = e >> 7, w = e & 127;
    tb[w*68 + ci] = f2bf(xp[(size_t)ci*TT*HW + w]);
  }
  __syncthreads();
  unsigned short* dst = xb + ((size_t)n*HW + (size_t)h*WW)*64;
  for (int e = tid; e < 2048; e += 256) {
    int w = e >> 4, c = e & 15;
    *(uint2*)(dst + w*64 + c*4) = *(const uint2*)(&tb[w*68 + c*4]);
  }
}

// ---- conv1 v6 (frozen, best-measured): both operands in LDS + B-frag reuse.
__global__ __launch_bounds__(256, 2) void conv1_mfma(
    const unsigned short* __restrict__ xb, const unsigned short* __restrict__ wb1,
    const float* __restrict__ b1, unsigned short* __restrict__ yb) {
  __shared__ unsigned short xt[324*64];    // 18x18 halo x 64 ic = 41472 B
  __shared__ unsigned short wt[36*512];    // 36 frags x 64 lanes x 8 shorts = 36864 B
  const int tid = threadIdx.x;
  const int wave = tid >> 6, lane = tid & 63, q = lane >> 4, r = lane & 15;
  const int n = blockIdx.z >> 1, ocg = (blockIdx.z & 1) << 5;
  const int h0 = blockIdx.y << 4, w0 = blockIdx.x << 4;
  const unsigned short* xn = xb + (size_t)n*HW*64;

  {
    const unsigned short* wsrc = wb1 + (size_t)ocg*576;
    for (int e = tid; e < 2304; e += 256) {
      int frag = e >> 6, ln = e & 63;
      int kk = frag >> 2, rem = frag & 3, half = rem >> 1, g = rem & 1;
      *(uint4*)(&wt[e << 3]) = *(const uint4*)(
          wsrc + (size_t)(g*16 + (ln & 15))*576 + kk*64 + half*32 + ((ln >> 4) << 3));
    }
  }
  for (int e = tid; e < 2592; e += 256) {           // 324 sp x 8 chunks, 16B
    int sp = e >> 3, c = e & 7;
    int sr = sp / 18, sc = sp - sr*18;
    int gh = h0 + sr - 1, gw = w0 + sc - 1;
    uint4 v = make_uint4(0u,0u,0u,0u);
    if (gh >= 0 && gh < HH && gw >= 0 && gw < WW)
      v = *(const uint4*)(xn + ((size_t)(gh*WW + gw))*64 + (c << 3));
    *(uint4*)(&xt[sp*64 + ((c ^ (sp & 7)) << 3)]) = v;
  }
  __syncthreads();

  f32x4 zero4 = {0.f, 0.f, 0.f, 0.f};
  f32x4 acc[4][2];
  #pragma unroll
  for (int i = 0; i < 4; ++i)
    #pragma unroll
    for (int g = 0; g < 2; ++g) acc[i][g] = zero4;

  #pragma unroll
  for (int half = 0; half < 2; ++half) {
    short8 bf[6][3];
    #pragma unroll
    for (int rr = 0; rr < 6; ++rr)
      #pragma unroll
      for (int dx = 0; dx < 3; ++dx) {
        int sp = (wave*4 + rr)*18 + (r + dx);
        bf[rr][dx] = *(const short8*)(&xt[sp*64 + ((((half << 2) | q) ^ (sp & 7)) << 3)]);
      }
    #pragma unroll
    for (int kk = 0; kk < 9; ++kk) {
      const int dy = kk / 3, dx = kk - dy*3;
      short8 a0 = *(const short8*)(&wt[((kk*4 + half*2 + 0) << 9) + (lane << 3)]);
      short8 a1 = *(const short8*)(&wt[((kk*4 + half*2 + 1) << 9) + (lane << 3)]);
      #pragma unroll
      for (int i = 0; i < 4; ++i) {
        acc[i][0] = __builtin_amdgcn_mfma_f32_16x16x32_bf16(a0, bf[i+dy][dx], acc[i][0], 0, 0, 0);
        acc[i][1] = __builtin_amdgcn_mfma_f32_16x16x32_bf16(a1, bf[i+dy][dx], acc[i][1], 0, 0, 0);
      }
    }
  }

  #pragma unroll
  for (int i = 0; i < 4; ++i) {
    int py = wave*4 + i;
    unsigned short* yp = yb + ((size_t)n*HW + (h0+py)*WW + (w0+r))*64;
    #pragma unroll
    for (int g = 0; g < 2; ++g) {
      int oc0 = ocg + g*16 + (q << 2);
      f32x4 bias = *(const f32x4*)(b1 + oc0);
      float v0 = acc[i][g][0] + bias[0]; v0 = (v0 >= 0.f) ? v0 : 0.2f*v0;
      float v1 = acc[i][g][1] + bias[1]; v1 = (v1 >= 0.f) ? v1 : 0.2f*v1;
      float v2 = acc[i][g][2] + bias[2]; v2 = (v2 >= 0.f) ? v2 : 0.2f*v2;
      float v3 = acc[i][g][3] + bias[3]; v3 = (v3 >= 0.f) ? v3 : 0.2f*v3;
      uint2 pk;
      pk.x = (unsigned int)f2bf(v0) | ((unsigned int)f2bf(v1) << 16);
      pk.y = (unsigned int)f2bf(v2) | ((unsigned int)f2bf(v3) << 16);
      *(uint2*)(yp + oc0) = pk;
    }
  }
}

// ---- conv2 v6 (frozen)
__global__ __launch_bounds__(256) void conv2_mfma(
    const unsigned short* __restrict__ yb, const unsigned short* __restrict__ wb2,
    const float* __restrict__ b2, float* __restrict__ ker0) {
  __shared__ unsigned short yt[180*64];
  __shared__ unsigned short wt[18*512];
  const int tid = threadIdx.x;
  const int wave = tid >> 6, lane = tid & 63, q = lane >> 4, r = lane & 15;
  const int n = blockIdx.z;
  const int h0 = blockIdx.y << 3, w0 = blockIdx.x << 4;
  const unsigned short* yn = yb + (size_t)n*HW*64;

  for (int e = tid; e < 1152; e += 256) {
    int frag = e >> 6, ln = e & 63;
    int kk = frag >> 1, half = frag & 1;
    *(uint4*)(&wt[e << 3]) = *(const uint4*)(
        wb2 + (size_t)(ln & 15)*576 + kk*64 + half*32 + ((ln >> 4) << 3));
  }
  for (int e = tid; e < 1440; e += 256) {
    int sp = e >> 3, c = e & 7;
    int sr = sp / 18, sc = sp - sr*18;
    int gh = h0 + sr - 1, gw = w0 + sc - 1;
    uint4 v = make_uint4(0u,0u,0u,0u);
    if (gh >= 0 && gh < HH && gw >= 0 && gw < WW)
      v = *(const uint4*)(yn + ((size_t)(gh*WW + gw))*64 + (c << 3));
    *(uint4*)(&yt[sp*64 + ((c ^ (sp & 7)) << 3)]) = v;
  }
  __syncthreads();

  f32x4 zero4 = {0.f, 0.f, 0.f, 0.f};
  f32x4 acc[2];
  #pragma unroll
  for (int i = 0; i < 2; ++i) acc[i] = zero4;

  #pragma unroll
  for (int half = 0; half < 2; ++half) {
    short8 bf[4][3];
    #pragma unroll
    for (int rr = 0; rr < 4; ++rr)
      #pragma unroll
      for (int dx = 0; dx < 3; ++dx) {
        int sp = (wave*2 + rr)*18 + (r + dx);
        bf[rr][dx] = *(const short8*)(&yt[sp*64 + ((((half << 2) | q) ^ (sp & 7)) << 3)]);
      }
    #pragma unroll
    for (int kk = 0; kk < 9; ++kk) {
      const int dy = kk / 3, dx = kk - dy*3;
      short8 a = *(const short8*)(&wt[((kk*2 + half) << 9) + (lane << 3)]);
      #pragma unroll
      for (int i = 0; i < 2; ++i)
        acc[i] = __builtin_amdgcn_mfma_f32_16x16x32_bf16(a, bf[i+dy][dx], acc[i], 0, 0, 0);
    }
  }

  #pragma unroll
  for (int i = 0; i < 2; ++i) {
    int py = wave*2 + i;
    #pragma unroll
    for (int t2 = 0; t2 < 4; ++t2) {
      int oc = (q << 2) + t2;
      if (oc < 9)
        ker0[((size_t)n*9 + oc)*HW + (h0+py)*WW + w0 + r] = acc[i][t2] + b2[oc];
    }
  }
}

// ---- dynamic filtering (R4-proven shape): 16x16 tile x 8 ci per block,
// grid (8,8,16). uint4 staging (full 16B loads), two fp32 planes, one barrier.
// Halves block count / ker0 re-reads / xb line over-fetch vs the 4-ci version.
__global__ __launch_bounds__(256) void dynf_k(
    const unsigned short* __restrict__ xb, const float* __restrict__ ker0,
    float* __restrict__ out) {
  __shared__ float xs0[TT*324*4];          // ci0..3, 25920 B
  __shared__ float xs1[TT*324*4];          // ci4..7, 25920 B
  const int tw = threadIdx.x, th = threadIdx.y;
  const int tid = th*16 + tw;
  const int wz = blockIdx.z;
  const int bi = wz >> 3, ci0 = (wz & 7) << 3;
  const int h0 = blockIdx.y << 4, w0 = blockIdx.x << 4;
  const int pix = (h0+th)*WW + w0 + tw;

  float kv[45]; float s = 0.f;
  #pragma unroll
  for (int t5 = 0; t5 < TT; ++t5)
    #pragma unroll
    for (int kk = 0; kk < 9; ++kk) {
      float v = ker0[((size_t)(bi*TT + t5)*9 + kk)*HW + pix];
      kv[t5*9 + kk] = v; s += v;
    }
  const float m = (s - 1.f) * (1.f/45.f);   // mean - 1/45
  #pragma unroll
  for (int qq = 0; qq < 45; ++qq) kv[qq] -= m;

  for (int e = tid; e < TT*324; e += 256) {
    int t5 = e / 324, sp = e - t5*324;
    int rr = sp / 18, cc = sp - rr*18;
    int gh = min(max(h0 + rr - 1, 0), HH-1);
    int gw = min(max(w0 + cc - 1, 0), WW-1);
    uint4 raw = *(const uint4*)(xb + ((size_t)(bi*TT + t5)*HW + gh*WW + gw)*64 + ci0);
    xs0[(e << 2) + 0] = bf2f(raw.x & 0xffffu);
    xs0[(e << 2) + 1] = bf2f(raw.x >> 16);
    xs0[(e << 2) + 2] = bf2f(raw.y & 0xffffu);
    xs0[(e << 2) + 3] = bf2f(raw.y >> 16);
    xs1[(e << 2) + 0] = bf2f(raw.z & 0xffffu);
    xs1[(e << 2) + 1] = bf2f(raw.z >> 16);
    xs1[(e << 2) + 2] = bf2f(raw.w & 0xffffu);
    xs1[(e << 2) + 3] = bf2f(raw.w >> 16);
  }
  __syncthreads();

  #pragma unroll
  for (int p = 0; p < 2; ++p) {
    const float* plane = p ? xs1 : xs0;
    float a0 = 0.f, a1 = 0.f, a2 = 0.f, a3 = 0.f;
    #pragma unroll
    for (int t5 = 0; t5 < TT; ++t5)
      #pragma unroll
      for (int dy = 0; dy < 3; ++dy)
        #pragma unroll
        for (int dx = 0; dx < 3; ++dx) {
          f32x4 xv = *(const f32x4*)(&plane[(t5*324 + (th+dy)*18 + (tw+dx)) << 2]);
          float k = kv[t5*9 + dy*3 + dx];
          a0 = fmaf(xv[0], k, a0); a1 = fmaf(xv[1], k, a1);
          a2 = fmaf(xv[2], k, a2); a3 = fmaf(xv[3], k, a3);
        }
    float* op = out + ((size_t)(bi*CC + ci0 + p*4))*HW + pix;
    op[0] = a0; op[HW] = a1; op[2*(size_t)HW] = a2; op[3*(size_t)HW] = a3;
  }
}

extern "C" void kernel_launch(void* const* d_in, const int* in_sizes, int n_in,
                              void* d_out, int out_size, void* d_ws, size_t ws_size,
                              hipStream_t stream) {
  const float* x  = (const float*)d_in[0];
  const float* w1 = (const float*)d_in[1];
  const float* b1 = (const float*)d_in[2];
  const float* w2 = (const float*)d_in[3];
  const float* b2 = (const float*)d_in[4];
  float* out = (float*)d_out;

  unsigned short* xb  = (unsigned short*)d_ws;
  unsigned short* yb  = xb + (size_t)NI*HW*64;
  float*          ker0 = (float*)(yb + (size_t)NI*HW*64);
  unsigned short* wb1 = (unsigned short*)(ker0 + (size_t)NI*9*HW);
  unsigned short* wb2 = wb1 + 64*576;

  pack_k    <<<NI*HH + 144, 256, 0, stream>>>(x, w1, w2, xb, wb1, wb2);
  conv1_mfma<<<dim3(8,8,2*NI), 256, 0, stream>>>(xb, wb1, b1, yb);
  conv2_mfma<<<dim3(8,16,NI), 256, 0, stream>>>(yb, wb2, b2, ker0);
  dynf_k    <<<dim3(8,8,16), dim3(16,16), 0, stream>>>(xb, ker0, out);
}

// Round 12
// 146.394 us; speedup vs baseline: 1.1655x; 1.0145x over previous
//
#include <hip/hip_runtime.h>
#include <hip/hip_bf16.h>

#define HH 128
#define WW 128
#define CC 64
#define TT 5
#define HW (HH*WW)
#define NI 10

typedef __attribute__((ext_vector_type(8))) short short8;
typedef __attribute__((ext_vector_type(4))) float f32x4;

typedef const unsigned int __attribute__((address_space(1))) gu32;
typedef unsigned int __attribute__((address_space(3))) lu32;

// async 16B global->LDS DMA; dst slot is wave-uniform base + lane*16
__device__ __forceinline__ void gl_lds16(const void* g, void* l) {
  __builtin_amdgcn_global_load_lds((gu32*)g, (lu32*)l, 16, 0, 0);
}

__device__ __forceinline__ float bf2f(unsigned int bits16) {
  union { unsigned int u; float f; } v; v.u = bits16 << 16; return v.f;
}
__device__ __forceinline__ unsigned short f2bf(float f) {
  __hip_bfloat16 h = __float2bfloat16(f);
  return *reinterpret_cast<unsigned short*>(&h);
}

// ---- merged pack (frozen): x transpose + weight pack.
__global__ __launch_bounds__(256) void pack_k(const float* __restrict__ x,
    const float* __restrict__ w1, const float* __restrict__ w2,
    unsigned short* __restrict__ xb, unsigned short* __restrict__ wb1,
    unsigned short* __restrict__ wb2) {
  __shared__ unsigned short tb[128*68];
  const int tid = threadIdx.x;
  const int bx = blockIdx.x;
  if (bx >= NI*HH) {            // ---- weight part
    int idx = (bx - NI*HH)*256 + tid;
    if (idx < 64*576) {
      int oc = idx / 576, rem = idx - oc*576, kk = rem >> 6, ic = rem & 63;
      wb1[idx] = f2bf(w1[(oc*64 + ic)*9 + kk]);
    }
    if (idx < 16*576) {
      int oc = idx / 576, rem = idx - oc*576, kk = rem >> 6, ic = rem & 63;
      wb2[idx] = (oc < 9) ? f2bf(w2[(oc*64 + ic)*9 + kk]) : (unsigned short)0;
    }
    return;
  }
  const int n = bx >> 7, h = bx & 127;
  const int bi = n / 5, ti = n - bi*5;
  const float* xp = x + ((size_t)bi*CC*TT + ti)*HW + (size_t)h*WW;
  for (int e = tid; e < 64*128; e += 256) {
    int ci = e >> 7, w = e & 127;
    tb[w*68 + ci] = f2bf(xp[(size_t)ci*TT*HW + w]);
  }
  __syncthreads();
  unsigned short* dst = xb + ((size_t)n*HW + (size_t)h*WW)*64;
  for (int e = tid; e < 2048; e += 256) {
    int w = e >> 4, c = e & 15;
    *(uint2*)(dst + w*64 + c*4) = *(const uint2*)(&tb[w*68 + c*4]);
  }
}

// ---- conv1 v7: v6 + async global_load_lds staging.
// Interior blocks (no OOB): both wt and xt staged via 16B DMA. The XOR swizzle
// moves to the SOURCE chunk index (slot s holds chunk s^(sp&7)), so the
// read-side swizzle is unchanged. Boundary blocks keep the VGPR path.
__global__ __launch_bounds__(256, 2) void conv1_mfma(
    const unsigned short* __restrict__ xb, const unsigned short* __restrict__ wb1,
    const float* __restrict__ b1, unsigned short* __restrict__ yb) {
  __shared__ unsigned short xt[324*64];    // 18x18 halo x 64 ic = 41472 B
  __shared__ unsigned short wt[36*512];    // 36 frags x 64 lanes x 8 shorts = 36864 B
  const int tid = threadIdx.x;
  const int wave = tid >> 6, lane = tid & 63, q = lane >> 4, r = lane & 15;
  const int n = blockIdx.z >> 1, ocg = (blockIdx.z & 1) << 5;
  const int h0 = blockIdx.y << 4, w0 = blockIdx.x << 4;
  const unsigned short* xn = xb + (size_t)n*HW*64;
  const int wbase = tid & ~63;             // wave*64, uniform within wave

  // ---- stage weights via async DMA (lane-linear dst, 9 full iterations)
  {
    const unsigned short* wsrc = wb1 + (size_t)ocg*576;
    #pragma unroll
    for (int it = 0; it < 9; ++it) {
      int e = tid + it*256;
      int frag = e >> 6, ln = e & 63;
      int kk = frag >> 2, rem = frag & 3, half = rem >> 1, g = rem & 1;
      const unsigned short* src = wsrc + (size_t)(g*16 + (ln & 15))*576
                                  + kk*64 + half*32 + ((ln >> 4) << 3);
      gl_lds16(src, (char*)wt + ((size_t)(it*256 + wbase) << 4));
    }
  }
  // ---- stage x halo tile
  const bool interior = (blockIdx.x >= 1) & (blockIdx.x <= 6) &
                        (blockIdx.y >= 1) & (blockIdx.y <= 6);
  if (interior) {
    #pragma unroll
    for (int it = 0; it < 11; ++it) {
      int e = tid + it*256;
      if (e < 2592) {
        int sp = e >> 3, c = e & 7;
        int cs = c ^ (sp & 7);                       // source-side swizzle
        int sr = sp / 18, sc = sp - sr*18;
        int gh = h0 + sr - 1, gw = w0 + sc - 1;
        const unsigned short* src = xn + ((size_t)(gh*WW + gw))*64 + (cs << 3);
        gl_lds16(src, (char*)xt + ((size_t)(it*256 + wbase) << 4));
      }
    }
  } else {
    for (int e = tid; e < 2592; e += 256) {          // 324 sp x 8 chunks, 16B
      int sp = e >> 3, c = e & 7;
      int sr = sp / 18, sc = sp - sr*18;
      int gh = h0 + sr - 1, gw = w0 + sc - 1;
      uint4 v = make_uint4(0u,0u,0u,0u);
      if (gh >= 0 && gh < HH && gw >= 0 && gw < WW)
        v = *(const uint4*)(xn + ((size_t)(gh*WW + gw))*64 + (c << 3));
      *(uint4*)(&xt[sp*64 + ((c ^ (sp & 7)) << 3)]) = v;
    }
  }
  __syncthreads();

  f32x4 zero4 = {0.f, 0.f, 0.f, 0.f};
  f32x4 acc[4][2];
  #pragma unroll
  for (int i = 0; i < 4; ++i)
    #pragma unroll
    for (int g = 0; g < 2; ++g) acc[i][g] = zero4;

  #pragma unroll
  for (int half = 0; half < 2; ++half) {
    short8 bf[6][3];
    #pragma unroll
    for (int rr = 0; rr < 6; ++rr)
      #pragma unroll
      for (int dx = 0; dx < 3; ++dx) {
        int sp = (wave*4 + rr)*18 + (r + dx);
        bf[rr][dx] = *(const short8*)(&xt[sp*64 + ((((half << 2) | q) ^ (sp & 7)) << 3)]);
      }
    #pragma unroll
    for (int kk = 0; kk < 9; ++kk) {
      const int dy = kk / 3, dx = kk - dy*3;
      short8 a0 = *(const short8*)(&wt[((kk*4 + half*2 + 0) << 9) + (lane << 3)]);
      short8 a1 = *(const short8*)(&wt[((kk*4 + half*2 + 1) << 9) + (lane << 3)]);
      #pragma unroll
      for (int i = 0; i < 4; ++i) {
        acc[i][0] = __builtin_amdgcn_mfma_f32_16x16x32_bf16(a0, bf[i+dy][dx], acc[i][0], 0, 0, 0);
        acc[i][1] = __builtin_amdgcn_mfma_f32_16x16x32_bf16(a1, bf[i+dy][dx], acc[i][1], 0, 0, 0);
      }
    }
  }

  #pragma unroll
  for (int i = 0; i < 4; ++i) {
    int py = wave*4 + i;
    unsigned short* yp = yb + ((size_t)n*HW + (h0+py)*WW + (w0+r))*64;
    #pragma unroll
    for (int g = 0; g < 2; ++g) {
      int oc0 = ocg + g*16 + (q << 2);
      f32x4 bias = *(const f32x4*)(b1 + oc0);
      float v0 = acc[i][g][0] + bias[0]; v0 = (v0 >= 0.f) ? v0 : 0.2f*v0;
      float v1 = acc[i][g][1] + bias[1]; v1 = (v1 >= 0.f) ? v1 : 0.2f*v1;
      float v2 = acc[i][g][2] + bias[2]; v2 = (v2 >= 0.f) ? v2 : 0.2f*v2;
      float v3 = acc[i][g][3] + bias[3]; v3 = (v3 >= 0.f) ? v3 : 0.2f*v3;
      uint2 pk;
      pk.x = (unsigned int)f2bf(v0) | ((unsigned int)f2bf(v1) << 16);
      pk.y = (unsigned int)f2bf(v2) | ((unsigned int)f2bf(v3) << 16);
      *(uint2*)(yp + oc0) = pk;
    }
  }
}

// ---- conv2 v7: same async-staging treatment. 16x8 tile, grid (8,16,10).
__global__ __launch_bounds__(256) void conv2_mfma(
    const unsigned short* __restrict__ yb, const unsigned short* __restrict__ wb2,
    const float* __restrict__ b2, float* __restrict__ ker0) {
  __shared__ unsigned short yt[180*64];    // 10x18 halo = 23040 B
  __shared__ unsigned short wt[18*512];    // 18 frags = 18432 B
  const int tid = threadIdx.x;
  const int wave = tid >> 6, lane = tid & 63, q = lane >> 4, r = lane & 15;
  const int n = blockIdx.z;
  const int h0 = blockIdx.y << 3, w0 = blockIdx.x << 4;
  const unsigned short* yn = yb + (size_t)n*HW*64;
  const int wbase = tid & ~63;

  // weights: 1152 elements = 4.5 iterations, async
  #pragma unroll
  for (int it = 0; it < 5; ++it) {
    int e = tid + it*256;
    if (e < 1152) {
      int frag = e >> 6, ln = e & 63;
      int kk = frag >> 1, half = frag & 1;
      const unsigned short* src = wb2 + (size_t)(ln & 15)*576 + kk*64
                                  + half*32 + ((ln >> 4) << 3);
      gl_lds16(src, (char*)wt + ((size_t)(it*256 + wbase) << 4));
    }
  }
  const bool interior = (blockIdx.x >= 1) & (blockIdx.x <= 6) &
                        (blockIdx.y >= 1) & (blockIdx.y <= 14);
  if (interior) {
    #pragma unroll
    for (int it = 0; it < 6; ++it) {
      int e = tid + it*256;
      if (e < 1440) {
        int sp = e >> 3, c = e & 7;
        int cs = c ^ (sp & 7);
        int sr = sp / 18, sc = sp - sr*18;
        int gh = h0 + sr - 1, gw = w0 + sc - 1;
        const unsigned short* src = yn + ((size_t)(gh*WW + gw))*64 + (cs << 3);
        gl_lds16(src, (char*)yt + ((size_t)(it*256 + wbase) << 4));
      }
    }
  } else {
    for (int e = tid; e < 1440; e += 256) {
      int sp = e >> 3, c = e & 7;
      int sr = sp / 18, sc = sp - sr*18;
      int gh = h0 + sr - 1, gw = w0 + sc - 1;
      uint4 v = make_uint4(0u,0u,0u,0u);
      if (gh >= 0 && gh < HH && gw >= 0 && gw < WW)
        v = *(const uint4*)(yn + ((size_t)(gh*WW + gw))*64 + (c << 3));
      *(uint4*)(&yt[sp*64 + ((c ^ (sp & 7)) << 3)]) = v;
    }
  }
  __syncthreads();

  f32x4 zero4 = {0.f, 0.f, 0.f, 0.f};
  f32x4 acc[2];
  #pragma unroll
  for (int i = 0; i < 2; ++i) acc[i] = zero4;

  #pragma unroll
  for (int half = 0; half < 2; ++half) {
    short8 bf[4][3];
    #pragma unroll
    for (int rr = 0; rr < 4; ++rr)
      #pragma unroll
      for (int dx = 0; dx < 3; ++dx) {
        int sp = (wave*2 + rr)*18 + (r + dx);
        bf[rr][dx] = *(const short8*)(&yt[sp*64 + ((((half << 2) | q) ^ (sp & 7)) << 3)]);
      }
    #pragma unroll
    for (int kk = 0; kk < 9; ++kk) {
      const int dy = kk / 3, dx = kk - dy*3;
      short8 a = *(const short8*)(&wt[((kk*2 + half) << 9) + (lane << 3)]);
      #pragma unroll
      for (int i = 0; i < 2; ++i)
        acc[i] = __builtin_amdgcn_mfma_f32_16x16x32_bf16(a, bf[i+dy][dx], acc[i], 0, 0, 0);
    }
  }

  #pragma unroll
  for (int i = 0; i < 2; ++i) {
    int py = wave*2 + i;
    #pragma unroll
    for (int t2 = 0; t2 < 4; ++t2) {
      int oc = (q << 2) + t2;
      if (oc < 9)
        ker0[((size_t)n*9 + oc)*HW + (h0+py)*WW + w0 + r] = acc[i][t2] + b2[oc];
    }
  }
}

// ---- dynamic filtering (frozen R11): 16x16 tile x 8 ci per block, grid (8,8,16).
__global__ __launch_bounds__(256) void dynf_k(
    const unsigned short* __restrict__ xb, const float* __restrict__ ker0,
    float* __restrict__ out) {
  __shared__ float xs0[TT*324*4];          // ci0..3, 25920 B
  __shared__ float xs1[TT*324*4];          // ci4..7, 25920 B
  const int tw = threadIdx.x, th = threadIdx.y;
  const int tid = th*16 + tw;
  const int wz = blockIdx.z;
  const int bi = wz >> 3, ci0 = (wz & 7) << 3;
  const int h0 = blockIdx.y << 4, w0 = blockIdx.x << 4;
  const int pix = (h0+th)*WW + w0 + tw;

  float kv[45]; float s = 0.f;
  #pragma unroll
  for (int t5 = 0; t5 < TT; ++t5)
    #pragma unroll
    for (int kk = 0; kk < 9; ++kk) {
      float v = ker0[((size_t)(bi*TT + t5)*9 + kk)*HW + pix];
      kv[t5*9 + kk] = v; s += v;
    }
  const float m = (s - 1.f) * (1.f/45.f);   // mean - 1/45
  #pragma unroll
  for (int qq = 0; qq < 45; ++qq) kv[qq] -= m;

  for (int e = tid; e < TT*324; e += 256) {
    int t5 = e / 324, sp = e - t5*324;
    int rr = sp / 18, cc = sp - rr*18;
    int gh = min(max(h0 + rr - 1, 0), HH-1);
    int gw = min(max(w0 + cc - 1, 0), WW-1);
    uint4 raw = *(const uint4*)(xb + ((size_t)(bi*TT + t5)*HW + gh*WW + gw)*64 + ci0);
    xs0[(e << 2) + 0] = bf2f(raw.x & 0xffffu);
    xs0[(e << 2) + 1] = bf2f(raw.x >> 16);
    xs0[(e << 2) + 2] = bf2f(raw.y & 0xffffu);
    xs0[(e << 2) + 3] = bf2f(raw.y >> 16);
    xs1[(e << 2) + 0] = bf2f(raw.z & 0xffffu);
    xs1[(e << 2) + 1] = bf2f(raw.z >> 16);
    xs1[(e << 2) + 2] = bf2f(raw.w & 0xffffu);
    xs1[(e << 2) + 3] = bf2f(raw.w >> 16);
  }
  __syncthreads();

  #pragma unroll
  for (int p = 0; p < 2; ++p) {
    const float* plane = p ? xs1 : xs0;
    float a0 = 0.f, a1 = 0.f, a2 = 0.f, a3 = 0.f;
    #pragma unroll
    for (int t5 = 0; t5 < TT; ++t5)
      #pragma unroll
      for (int dy = 0; dy < 3; ++dy)
        #pragma unroll
        for (int dx = 0; dx < 3; ++dx) {
          f32x4 xv = *(const f32x4*)(&plane[(t5*324 + (th+dy)*18 + (tw+dx)) << 2]);
          float k = kv[t5*9 + dy*3 + dx];
          a0 = fmaf(xv[0], k, a0); a1 = fmaf(xv[1], k, a1);
          a2 = fmaf(xv[2], k, a2); a3 = fmaf(xv[3], k, a3);
        }
    float* op = out + ((size_t)(bi*CC + ci0 + p*4))*HW + pix;
    op[0] = a0; op[HW] = a1; op[2*(size_t)HW] = a2; op[3*(size_t)HW] = a3;
  }
}

extern "C" void kernel_launch(void* const* d_in, const int* in_sizes, int n_in,
                              void* d_out, int out_size, void* d_ws, size_t ws_size,
                              hipStream_t stream) {
  const float* x  = (const float*)d_in[0];
  const float* w1 = (const float*)d_in[1];
  const float* b1 = (const float*)d_in[2];
  const float* w2 = (const float*)d_in[3];
  const float* b2 = (const float*)d_in[4];
  float* out = (float*)d_out;

  unsigned short* xb  = (unsigned short*)d_ws;
  unsigned short* yb  = xb + (size_t)NI*HW*64;
  float*          ker0 = (float*)(yb + (size_t)NI*HW*64);
  unsigned short* wb1 = (unsigned short*)(ker0 + (size_t)NI*9*HW);
  unsigned short* wb2 = wb1 + 64*576;

  pack_k    <<<NI*HH + 144, 256, 0, stream>>>(x, w1, w2, xb, wb1, wb2);
  conv1_mfma<<<dim3(8,8,2*NI), 256, 0, stream>>>(xb, wb1, b1, yb);
  conv2_mfma<<<dim3(8,16,NI), 256, 0, stream>>>(yb, wb2, b2, ker0);
  dynf_k    <<<dim3(8,8,16), dim3(16,16), 0, stream>>>(xb, ker0, out);
}

// Round 13
// 144.671 us; speedup vs baseline: 1.1793x; 1.0119x over previous
//
#include <hip/hip_runtime.h>
#include <hip/hip_bf16.h>

#define HH 128
#define WW 128
#define CC 64
#define TT 5
#define HW (HH*WW)
#define NI 10

typedef __attribute__((ext_vector_type(8))) short short8;
typedef __attribute__((ext_vector_type(4))) float f32x4;

typedef const unsigned int __attribute__((address_space(1))) gu32;
typedef unsigned int __attribute__((address_space(3))) lu32;

__device__ __forceinline__ void gl_lds16(const void* g, void* l) {
  __builtin_amdgcn_global_load_lds((gu32*)g, (lu32*)l, 16, 0, 0);
}

__device__ __forceinline__ float bf2f(unsigned int bits16) {
  union { unsigned int u; float f; } v; v.u = bits16 << 16; return v.f;
}
__device__ __forceinline__ unsigned short f2bf(float f) {
  __hip_bfloat16 h = __float2bfloat16(f);
  return *reinterpret_cast<unsigned short*>(&h);
}

// ---- merged pack (frozen)
__global__ __launch_bounds__(256) void pack_k(const float* __restrict__ x,
    const float* __restrict__ w1, const float* __restrict__ w2,
    unsigned short* __restrict__ xb, unsigned short* __restrict__ wb1,
    unsigned short* __restrict__ wb2) {
  __shared__ unsigned short tb[128*68];
  const int tid = threadIdx.x;
  const int bx = blockIdx.x;
  if (bx >= NI*HH) {
    int idx = (bx - NI*HH)*256 + tid;
    if (idx < 64*576) {
      int oc = idx / 576, rem = idx - oc*576, kk = rem >> 6, ic = rem & 63;
      wb1[idx] = f2bf(w1[(oc*64 + ic)*9 + kk]);
    }
    if (idx < 16*576) {
      int oc = idx / 576, rem = idx - oc*576, kk = rem >> 6, ic = rem & 63;
      wb2[idx] = (oc < 9) ? f2bf(w2[(oc*64 + ic)*9 + kk]) : (unsigned short)0;
    }
    return;
  }
  const int n = bx >> 7, h = bx & 127;
  const int bi = n / 5, ti = n - bi*5;
  const float* xp = x + ((size_t)bi*CC*TT + ti)*HW + (size_t)h*WW;
  for (int e = tid; e < 64*128; e += 256) {
    int ci = e >> 7, w = e & 127;
    tb[w*68 + ci] = f2bf(xp[(size_t)ci*TT*HW + w]);
  }
  __syncthreads();
  unsigned short* dst = xb + ((size_t)n*HW + (size_t)h*WW)*64;
  for (int e = tid; e < 2048; e += 256) {
    int w = e >> 4, c = e & 15;
    *(uint2*)(dst + w*64 + c*4) = *(const uint2*)(&tb[w*68 + c*4]);
  }
}

// ---- conv1 v7 (frozen from R12): async DMA staging, source-side swizzle.
__global__ __launch_bounds__(256, 2) void conv1_mfma(
    const unsigned short* __restrict__ xb, const unsigned short* __restrict__ wb1,
    const float* __restrict__ b1, unsigned short* __restrict__ yb) {
  __shared__ unsigned short xt[324*64];
  __shared__ unsigned short wt[36*512];
  const int tid = threadIdx.x;
  const int wave = tid >> 6, lane = tid & 63, q = lane >> 4, r = lane & 15;
  const int n = blockIdx.z >> 1, ocg = (blockIdx.z & 1) << 5;
  const int h0 = blockIdx.y << 4, w0 = blockIdx.x << 4;
  const unsigned short* xn = xb + (size_t)n*HW*64;
  const int wbase = tid & ~63;

  {
    const unsigned short* wsrc = wb1 + (size_t)ocg*576;
    #pragma unroll
    for (int it = 0; it < 9; ++it) {
      int e = tid + it*256;
      int frag = e >> 6, ln = e & 63;
      int kk = frag >> 2, rem = frag & 3, half = rem >> 1, g = rem & 1;
      const unsigned short* src = wsrc + (size_t)(g*16 + (ln & 15))*576
                                  + kk*64 + half*32 + ((ln >> 4) << 3);
      gl_lds16(src, (char*)wt + ((size_t)(it*256 + wbase) << 4));
    }
  }
  const bool interior = (blockIdx.x >= 1) & (blockIdx.x <= 6) &
                        (blockIdx.y >= 1) & (blockIdx.y <= 6);
  if (interior) {
    #pragma unroll
    for (int it = 0; it < 11; ++it) {
      int e = tid + it*256;
      if (e < 2592) {
        int sp = e >> 3, c = e & 7;
        int cs = c ^ (sp & 7);
        int sr = sp / 18, sc = sp - sr*18;
        int gh = h0 + sr - 1, gw = w0 + sc - 1;
        const unsigned short* src = xn + ((size_t)(gh*WW + gw))*64 + (cs << 3);
        gl_lds16(src, (char*)xt + ((size_t)(it*256 + wbase) << 4));
      }
    }
  } else {
    for (int e = tid; e < 2592; e += 256) {
      int sp = e >> 3, c = e & 7;
      int sr = sp / 18, sc = sp - sr*18;
      int gh = h0 + sr - 1, gw = w0 + sc - 1;
      uint4 v = make_uint4(0u,0u,0u,0u);
      if (gh >= 0 && gh < HH && gw >= 0 && gw < WW)
        v = *(const uint4*)(xn + ((size_t)(gh*WW + gw))*64 + (c << 3));
      *(uint4*)(&xt[sp*64 + ((c ^ (sp & 7)) << 3)]) = v;
    }
  }
  __syncthreads();

  f32x4 zero4 = {0.f, 0.f, 0.f, 0.f};
  f32x4 acc[4][2];
  #pragma unroll
  for (int i = 0; i < 4; ++i)
    #pragma unroll
    for (int g = 0; g < 2; ++g) acc[i][g] = zero4;

  #pragma unroll
  for (int half = 0; half < 2; ++half) {
    short8 bf[6][3];
    #pragma unroll
    for (int rr = 0; rr < 6; ++rr)
      #pragma unroll
      for (int dx = 0; dx < 3; ++dx) {
        int sp = (wave*4 + rr)*18 + (r + dx);
        bf[rr][dx] = *(const short8*)(&xt[sp*64 + ((((half << 2) | q) ^ (sp & 7)) << 3)]);
      }
    #pragma unroll
    for (int kk = 0; kk < 9; ++kk) {
      const int dy = kk / 3, dx = kk - dy*3;
      short8 a0 = *(const short8*)(&wt[((kk*4 + half*2 + 0) << 9) + (lane << 3)]);
      short8 a1 = *(const short8*)(&wt[((kk*4 + half*2 + 1) << 9) + (lane << 3)]);
      #pragma unroll
      for (int i = 0; i < 4; ++i) {
        acc[i][0] = __builtin_amdgcn_mfma_f32_16x16x32_bf16(a0, bf[i+dy][dx], acc[i][0], 0, 0, 0);
        acc[i][1] = __builtin_amdgcn_mfma_f32_16x16x32_bf16(a1, bf[i+dy][dx], acc[i][1], 0, 0, 0);
      }
    }
  }

  #pragma unroll
  for (int i = 0; i < 4; ++i) {
    int py = wave*4 + i;
    unsigned short* yp = yb + ((size_t)n*HW + (h0+py)*WW + (w0+r))*64;
    #pragma unroll
    for (int g = 0; g < 2; ++g) {
      int oc0 = ocg + g*16 + (q << 2);
      f32x4 bias = *(const f32x4*)(b1 + oc0);
      float v0 = acc[i][g][0] + bias[0]; v0 = (v0 >= 0.f) ? v0 : 0.2f*v0;
      float v1 = acc[i][g][1] + bias[1]; v1 = (v1 >= 0.f) ? v1 : 0.2f*v1;
      float v2 = acc[i][g][2] + bias[2]; v2 = (v2 >= 0.f) ? v2 : 0.2f*v2;
      float v3 = acc[i][g][3] + bias[3]; v3 = (v3 >= 0.f) ? v3 : 0.2f*v3;
      uint2 pk;
      pk.x = (unsigned int)f2bf(v0) | ((unsigned int)f2bf(v1) << 16);
      pk.y = (unsigned int)f2bf(v2) | ((unsigned int)f2bf(v3) << 16);
      *(uint2*)(yp + oc0) = pk;
    }
  }
}

// ---- conv2 v7 (frozen from R12)
__global__ __launch_bounds__(256) void conv2_mfma(
    const unsigned short* __restrict__ yb, const unsigned short* __restrict__ wb2,
    const float* __restrict__ b2, float* __restrict__ ker0) {
  __shared__ unsigned short yt[180*64];
  __shared__ unsigned short wt[18*512];
  const int tid = threadIdx.x;
  const int wave = tid >> 6, lane = tid & 63, q = lane >> 4, r = lane & 15;
  const int n = blockIdx.z;
  const int h0 = blockIdx.y << 3, w0 = blockIdx.x << 4;
  const unsigned short* yn = yb + (size_t)n*HW*64;
  const int wbase = tid & ~63;

  #pragma unroll
  for (int it = 0; it < 5; ++it) {
    int e = tid + it*256;
    if (e < 1152) {
      int frag = e >> 6, ln = e & 63;
      int kk = frag >> 1, half = frag & 1;
      const unsigned short* src = wb2 + (size_t)(ln & 15)*576 + kk*64
                                  + half*32 + ((ln >> 4) << 3);
      gl_lds16(src, (char*)wt + ((size_t)(it*256 + wbase) << 4));
    }
  }
  const bool interior = (blockIdx.x >= 1) & (blockIdx.x <= 6) &
                        (blockIdx.y >= 1) & (blockIdx.y <= 14);
  if (interior) {
    #pragma unroll
    for (int it = 0; it < 6; ++it) {
      int e = tid + it*256;
      if (e < 1440) {
        int sp = e >> 3, c = e & 7;
        int cs = c ^ (sp & 7);
        int sr = sp / 18, sc = sp - sr*18;
        int gh = h0 + sr - 1, gw = w0 + sc - 1;
        const unsigned short* src = yn + ((size_t)(gh*WW + gw))*64 + (cs << 3);
        gl_lds16(src, (char*)yt + ((size_t)(it*256 + wbase) << 4));
      }
    }
  } else {
    for (int e = tid; e < 1440; e += 256) {
      int sp = e >> 3, c = e & 7;
      int sr = sp / 18, sc = sp - sr*18;
      int gh = h0 + sr - 1, gw = w0 + sc - 1;
      uint4 v = make_uint4(0u,0u,0u,0u);
      if (gh >= 0 && gh < HH && gw >= 0 && gw < WW)
        v = *(const uint4*)(yn + ((size_t)(gh*WW + gw))*64 + (c << 3));
      *(uint4*)(&yt[sp*64 + ((c ^ (sp & 7)) << 3)]) = v;
    }
  }
  __syncthreads();

  f32x4 zero4 = {0.f, 0.f, 0.f, 0.f};
  f32x4 acc[2];
  #pragma unroll
  for (int i = 0; i < 2; ++i) acc[i] = zero4;

  #pragma unroll
  for (int half = 0; half < 2; ++half) {
    short8 bf[4][3];
    #pragma unroll
    for (int rr = 0; rr < 4; ++rr)
      #pragma unroll
      for (int dx = 0; dx < 3; ++dx) {
        int sp = (wave*2 + rr)*18 + (r + dx);
        bf[rr][dx] = *(const short8*)(&yt[sp*64 + ((((half << 2) | q) ^ (sp & 7)) << 3)]);
      }
    #pragma unroll
    for (int kk = 0; kk < 9; ++kk) {
      const int dy = kk / 3, dx = kk - dy*3;
      short8 a = *(const short8*)(&wt[((kk*2 + half) << 9) + (lane << 3)]);
      #pragma unroll
      for (int i = 0; i < 2; ++i)
        acc[i] = __builtin_amdgcn_mfma_f32_16x16x32_bf16(a, bf[i+dy][dx], acc[i], 0, 0, 0);
    }
  }

  #pragma unroll
  for (int i = 0; i < 2; ++i) {
    int py = wave*2 + i;
    #pragma unroll
    for (int t2 = 0; t2 < 4; ++t2) {
      int oc = (q << 2) + t2;
      if (oc < 9)
        ker0[((size_t)n*9 + oc)*HW + (h0+py)*WW + w0 + r] = acc[i][t2] + b2[oc];
    }
  }
}

// ---- dynamic filtering v6: 16x16 tile x 16 ci per block (2 octet-rounds
// reusing the same xs planes). Halves ker0/kv redundancy (188->94 MB L2) and
// xb line over-fetch vs the 8-ci version. LDS 51.8 KB -> 3 blocks/CU.
// grid (8,8,8): wz = bi*4 + cio.
__global__ __launch_bounds__(256) void dynf_k(
    const unsigned short* __restrict__ xb, const float* __restrict__ ker0,
    float* __restrict__ out) {
  __shared__ float xs0[TT*324*4];          // 25920 B
  __shared__ float xs1[TT*324*4];          // 25920 B
  const int tw = threadIdx.x, th = threadIdx.y;
  const int tid = th*16 + tw;
  const int wz = blockIdx.z;
  const int bi = wz >> 2, cio = (wz & 3) << 4;
  const int h0 = blockIdx.y << 4, w0 = blockIdx.x << 4;
  const int pix = (h0+th)*WW + w0 + tw;

  float kv[45]; float s = 0.f;
  #pragma unroll
  for (int t5 = 0; t5 < TT; ++t5)
    #pragma unroll
    for (int kk = 0; kk < 9; ++kk) {
      float v = ker0[((size_t)(bi*TT + t5)*9 + kk)*HW + pix];
      kv[t5*9 + kk] = v; s += v;
    }
  const float m = (s - 1.f) * (1.f/45.f);   // mean - 1/45
  #pragma unroll
  for (int qq = 0; qq < 45; ++qq) kv[qq] -= m;

  for (int co = 0; co < 2; ++co) {
    const int ci0 = cio + (co << 3);
    __syncthreads();                        // xs consumed by previous round
    for (int e = tid; e < TT*324; e += 256) {
      int t5 = e / 324, sp = e - t5*324;
      int rr = sp / 18, cc = sp - rr*18;
      int gh = min(max(h0 + rr - 1, 0), HH-1);
      int gw = min(max(w0 + cc - 1, 0), WW-1);
      uint4 raw = *(const uint4*)(xb + ((size_t)(bi*TT + t5)*HW + gh*WW + gw)*64 + ci0);
      xs0[(e << 2) + 0] = bf2f(raw.x & 0xffffu);
      xs0[(e << 2) + 1] = bf2f(raw.x >> 16);
      xs0[(e << 2) + 2] = bf2f(raw.y & 0xffffu);
      xs0[(e << 2) + 3] = bf2f(raw.y >> 16);
      xs1[(e << 2) + 0] = bf2f(raw.z & 0xffffu);
      xs1[(e << 2) + 1] = bf2f(raw.z >> 16);
      xs1[(e << 2) + 2] = bf2f(raw.w & 0xffffu);
      xs1[(e << 2) + 3] = bf2f(raw.w >> 16);
    }
    __syncthreads();

    #pragma unroll
    for (int p = 0; p < 2; ++p) {
      const float* plane = p ? xs1 : xs0;
      float a0 = 0.f, a1 = 0.f, a2 = 0.f, a3 = 0.f;
      #pragma unroll
      for (int t5 = 0; t5 < TT; ++t5)
        #pragma unroll
        for (int dy = 0; dy < 3; ++dy)
          #pragma unroll
          for (int dx = 0; dx < 3; ++dx) {
            f32x4 xv = *(const f32x4*)(&plane[(t5*324 + (th+dy)*18 + (tw+dx)) << 2]);
            float k = kv[t5*9 + dy*3 + dx];
            a0 = fmaf(xv[0], k, a0); a1 = fmaf(xv[1], k, a1);
            a2 = fmaf(xv[2], k, a2); a3 = fmaf(xv[3], k, a3);
          }
      float* op = out + ((size_t)(bi*CC + ci0 + p*4))*HW + pix;
      op[0] = a0; op[HW] = a1; op[2*(size_t)HW] = a2; op[3*(size_t)HW] = a3;
    }
  }
}

extern "C" void kernel_launch(void* const* d_in, const int* in_sizes, int n_in,
                              void* d_out, int out_size, void* d_ws, size_t ws_size,
                              hipStream_t stream) {
  const float* x  = (const float*)d_in[0];
  const float* w1 = (const float*)d_in[1];
  const float* b1 = (const float*)d_in[2];
  const float* w2 = (const float*)d_in[3];
  const float* b2 = (const float*)d_in[4];
  float* out = (float*)d_out;

  unsigned short* xb  = (unsigned short*)d_ws;
  unsigned short* yb  = xb + (size_t)NI*HW*64;
  float*          ker0 = (float*)(yb + (size_t)NI*HW*64);
  unsigned short* wb1 = (unsigned short*)(ker0 + (size_t)NI*9*HW);
  unsigned short* wb2 = wb1 + 64*576;

  pack_k    <<<NI*HH + 144, 256, 0, stream>>>(x, w1, w2, xb, wb1, wb2);
  conv1_mfma<<<dim3(8,8,2*NI), 256, 0, stream>>>(xb, wb1, b1, yb);
  conv2_mfma<<<dim3(8,16,NI), 256, 0, stream>>>(yb, wb2, b2, ker0);
  dynf_k    <<<dim3(8,8,8), dim3(16,16), 0, stream>>>(xb, ker0, out);
}